// Round 15
// baseline (3678.876 us; speedup 1.0000x reference)
//
#include <hip/hip_runtime.h>
#include <math.h>

#define FEAT 1024
#define NB 16       // batch
#define NT 256      // seq len
#define VOCAB 32000
#define G3 3072     // 3*FEAT
#define NWG 256     // scan blocks per layer
#define FLAG_STRIDE 32   // 128B between flags
#define NGRP 8
#define GSZ 32
#define NXPT 24     // n-tiles per xp m-tile (G3/128)

#define BK 32       // K-step of the MFMA GEMM
#define LDH 40      // f16 row stride in LDS
#define SMEM_BYTES 75584

typedef float f4 __attribute__((ext_vector_type(4)));
typedef float f32x4 __attribute__((ext_vector_type(4)));
typedef _Float16 half4v __attribute__((ext_vector_type(4)));
typedef _Float16 half8v __attribute__((ext_vector_type(8)));

// ---------------- embedding gather ----------------
__global__ __launch_bounds__(256) void gather_kernel(const int* __restrict__ x,
                                                     const float* __restrict__ emb,
                                                     float* __restrict__ xs) {
    int row = blockIdx.x;
    int t = row >> 4;
    int b = row & 15;
    int tok = x[b * NT + t];
    const float4* src = (const float4*)(emb + (size_t)tok * FEAT);
    float4* dst = (float4*)(xs + (size_t)row * FEAT);
    dst[threadIdx.x] = src[threadIdx.x];
}

// ---------------- agent-coherent store (LLC) ----------------
__device__ __forceinline__ void store_f32_sc(float* p, float v) {
    asm volatile("global_store_dword %0, %1, off sc0 sc1" :: "v"(p), "v"(v) : "memory");
}
// verified 2-hop barrier primitives (round 10/13/14)
__device__ __forceinline__ void bar_arrive(unsigned* flag, unsigned expected) {
    asm volatile("s_waitcnt vmcnt(0)\n\t"
                 "global_store_dword %0, %1, off sc0 sc1"
                 :: "v"(flag), "v"(expected) : "memory");
}
__device__ __forceinline__ void bar_poll(const unsigned* p, unsigned expected) {
    unsigned v; int spins = 0;
    while (true) {
        asm volatile("global_load_dword %0, %1, off sc0 sc1\n\t"
                     "s_waitcnt vmcnt(0)"
                     : "=&v"(v) : "v"(p) : "memory");
        if (v >= expected) break;
        if (++spins > (1 << 20)) break;   // safety valve
        __builtin_amdgcn_s_sleep(1);
    }
}

// ---------------- split-f16 MFMA GEMM tile (verified body) ----------
// coherent!=0: C stored with sc0/sc1 (writethrough to LLC) and, if cnt!=NULL,
// per-wave vmcnt drain + syncthreads + one device-scope counter increment.
__device__ __forceinline__ void gemm_tile(char* smemraw,
        const float* __restrict__ A, const float* __restrict__ Bm,
        const float* __restrict__ bias, float* __restrict__ C,
        int N, int K, int m_t, int n_t, int perm,
        int coherent, unsigned* cnt) {
    _Float16* AhS = (_Float16*)smemraw;
    _Float16* AlS = AhS + 128 * LDH;
    _Float16* BhS = AlS + 128 * LDH;
    _Float16* BlS = BhS + 128 * LDH;

    int tid = threadIdx.x;
    int srow = tid >> 1;
    int shf = tid & 1;

    const float* aptr = A + (size_t)(m_t * 128 + srow) * K + shf * 16;
    const float* bptr = Bm + (size_t)(n_t * 128 + srow) * K + shf * 16;

    int wid = tid >> 6;
    int wr = wid >> 1, wc = wid & 1;
    int lane = tid & 63;
    int fr = lane & 15;
    int ke = lane >> 4;

    f32x4 acc[4][4];
#pragma unroll
    for (int i = 0; i < 4; i++)
#pragma unroll
        for (int j = 0; j < 4; j++) acc[i][j] = (f32x4){0.f, 0.f, 0.f, 0.f};

    float4 a4[4], b4[4];
#pragma unroll
    for (int q = 0; q < 4; q++) {
        a4[q] = *(const float4*)(aptr + q * 4);
        b4[q] = *(const float4*)(bptr + q * 4);
    }

    for (int k0 = 0; k0 < K; k0 += BK) {
        __syncthreads();
#pragma unroll
        for (int q = 0; q < 4; q++) {
            half4v hh, hl;
            hh.x = (_Float16)a4[q].x; hl.x = (_Float16)(a4[q].x - (float)hh.x);
            hh.y = (_Float16)a4[q].y; hl.y = (_Float16)(a4[q].y - (float)hh.y);
            hh.z = (_Float16)a4[q].z; hl.z = (_Float16)(a4[q].z - (float)hh.z);
            hh.w = (_Float16)a4[q].w; hl.w = (_Float16)(a4[q].w - (float)hh.w);
            int o = srow * LDH + shf * 16 + q * 4;
            *(half4v*)&AhS[o] = hh;
            *(half4v*)&AlS[o] = hl;
            half4v gh, gl;
            gh.x = (_Float16)b4[q].x; gl.x = (_Float16)(b4[q].x - (float)gh.x);
            gh.y = (_Float16)b4[q].y; gl.y = (_Float16)(b4[q].y - (float)gh.y);
            gh.z = (_Float16)b4[q].z; gl.z = (_Float16)(b4[q].z - (float)gh.z);
            gh.w = (_Float16)b4[q].w; gl.w = (_Float16)(b4[q].w - (float)gh.w);
            *(half4v*)&BhS[o] = gh;
            *(half4v*)&BlS[o] = gl;
        }
        __syncthreads();

        if (k0 + BK < K) {
#pragma unroll
            for (int q = 0; q < 4; q++) {
                a4[q] = *(const float4*)(aptr + k0 + BK + q * 4);
                b4[q] = *(const float4*)(bptr + k0 + BK + q * 4);
            }
        }

        half8v ah[4], al[4], bh[4], bl[4];
#pragma unroll
        for (int i = 0; i < 4; i++) {
            int ao = (wr * 64 + i * 16 + fr) * LDH + ke * 8;
            ah[i] = *(const half8v*)&AhS[ao];
            al[i] = *(const half8v*)&AlS[ao];
            int bo = (wc * 64 + i * 16 + fr) * LDH + ke * 8;
            bh[i] = *(const half8v*)&BhS[bo];
            bl[i] = *(const half8v*)&BlS[bo];
        }
#pragma unroll
        for (int i = 0; i < 4; i++)
#pragma unroll
            for (int j = 0; j < 4; j++) {
                acc[i][j] = __builtin_amdgcn_mfma_f32_16x16x32_f16(ah[i], bh[j], acc[i][j], 0, 0, 0);
                acc[i][j] = __builtin_amdgcn_mfma_f32_16x16x32_f16(ah[i], bl[j], acc[i][j], 0, 0, 0);
                acc[i][j] = __builtin_amdgcn_mfma_f32_16x16x32_f16(al[i], bh[j], acc[i][j], 0, 0, 0);
            }
    }

#pragma unroll
    for (int j = 0; j < 4; j++) {
        int col = n_t * 128 + wc * 64 + j * 16 + fr;
        float bv = bias[col];
#pragma unroll
        for (int i = 0; i < 4; i++) {
#pragma unroll
            for (int v = 0; v < 4; v++) {
                int mrow = m_t * 128 + wr * 64 + i * 16 + 4 * ke + v;
                int orow = perm ? (((mrow & 15) << 8) | (mrow >> 4)) : mrow;
                float val = acc[i][j][v] + bv;
                if (coherent) store_f32_sc(&C[(size_t)orow * N + col], val);
                else          C[(size_t)orow * N + col] = val;
            }
        }
    }
    if (cnt) {
        asm volatile("s_waitcnt vmcnt(0)" ::: "memory");   // this wave's sc1 stores at LLC
        __syncthreads();                                   // all waves drained
        if (tid == 0)
            __hip_atomic_fetch_add(cnt, 1u, __ATOMIC_RELAXED, __HIP_MEMORY_SCOPE_AGENT);
    }
}

// ---------------- persistent scan layer (round-10/14 verified structure) -------
// xpcnt != NULL: step t's xp reads gated on xpcnt[t>>3] == NXPT (producer-side
// counter, polled in the PREVIOUS step's barrier window; ordered by its final
// __syncthreads). xp gate-value loads at loop top (latency hides under matvec).
// All scan waves run at s_setprio(1) so co-resident GEMM waves don't starve
// the latency-critical scan (T5: helps only with role-diverse waves).
__device__ __forceinline__ void scan_layer(char* smemraw,
        const float* __restrict__ xp, const float* __restrict__ Whh,
        const float* __restrict__ bhh, const float* __restrict__ h0src,
        float* __restrict__ ys, float* __restrict__ hid,
        unsigned* __restrict__ flags, unsigned* __restrict__ gflags,
        const unsigned* __restrict__ xpcnt) {
    float* w_lds   = (float*)smemraw;        // 12*1024
    float* red     = w_lds + 12 * 1024;      // 192*33
    float* sums    = red + 192 * 33;         // 256
    float* bhh_lds = sums + 256;             // 12

    __builtin_amdgcn_s_setprio(1);

    int wg = blockIdx.x;
    int j0 = wg * 4;
    int tid = threadIdx.x;

    for (int rr = 0; rr < 12; rr++) {
        int gate = rr >> 2, jloc = rr & 3;
        int grow = gate * FEAT + j0 + jloc;
        float4 v = ((const float4*)(Whh + (size_t)grow * FEAT))[tid];
        *(float4*)(w_lds + rr * 1024 + tid * 4) = v;
    }
    if (tid < 12) {
        int gate = tid >> 2, jloc = tid & 3;
        bhh_lds[tid] = bhh[gate * FEAT + j0 + jloc];
    }
    if (xpcnt && tid == 0) bar_poll(&xpcnt[0], NXPT);   // gate for t=0 xp rows
    __syncthreads();

    int bg = tid >> 6;        // 0..3 batch group
    int kc = tid & 63;        // 0..63 k chunk
    int pb = tid >> 2, pjl = tid & 3, pj = j0 + pjl;   // gating map (tid<64)

    float hreg = 0.f;
    if (tid < 64) hreg = h0src[pb * FEAT + pj];

    for (int t = 0; t < NT; t++) {
        // xp gate values for THIS step (plain loads; latency hides under matvec)
        float xr = 0.f, xz = 0.f, xnv = 0.f;
        if (tid < 64) {
            const float* xpr = xp + (size_t)(t * NB + pb) * G3;
            xr = xpr[pj]; xz = xpr[FEAT + pj]; xnv = xpr[2 * FEAT + pj];
        }

        const float* hc = (t == 0) ? h0src : (ys + (size_t)(t - 1) * NB * FEAT);
        f4 h4[16];
#pragma unroll
        for (int bi = 0; bi < 4; bi++) {
            const float* hp = hc + (size_t)(bg * 4 + bi) * FEAT + kc * 4;
#pragma unroll
            for (int q = 0; q < 4; q++)
                h4[bi * 4 + q] = *(const f4*)(hp + q * 256);
        }

        float part[48];
#pragma unroll
        for (int i = 0; i < 48; i++) part[i] = 0.f;
#pragma unroll
        for (int q = 0; q < 4; q++) {
            int kof = q * 256 + kc * 4;
#pragma unroll
            for (int rr = 0; rr < 12; rr++) {
                f4 w = *(const f4*)&w_lds[rr * 1024 + kof];
#pragma unroll
                for (int bi = 0; bi < 4; bi++) {
                    f4 h = h4[bi * 4 + q];
                    float p = part[rr * 4 + bi];
                    p = fmaf(h.x, w.x, p); p = fmaf(h.y, w.y, p);
                    p = fmaf(h.z, w.z, p); p = fmaf(h.w, w.w, p);
                    part[rr * 4 + bi] = p;
                }
            }
        }
#pragma unroll
        for (int i = 0; i < 48; i++) part[i] += __shfl_xor(part[i], 1);
        if ((kc & 1) == 0) {
#pragma unroll
            for (int rr = 0; rr < 12; rr++)
#pragma unroll
                for (int bi = 0; bi < 4; bi++)
                    red[(rr * 16 + bg * 4 + bi) * 33 + (kc >> 1)] = part[rr * 4 + bi];
        }
        __syncthreads();

        if (tid < 192) {
            float s = 0.f;
#pragma unroll
            for (int c = 0; c < 32; c++) s += red[tid * 33 + c];
            sums[tid] = s;
        }
        __syncthreads();

        if (tid < 64) {
            float dr = sums[pjl * 16 + pb] + bhh_lds[pjl];
            float dz = sums[(4 + pjl) * 16 + pb] + bhh_lds[4 + pjl];
            float dn = sums[(8 + pjl) * 16 + pb] + bhh_lds[8 + pjl];
            float r = 1.f / (1.f + expf(-(xr + dr)));
            float z = 1.f / (1.f + expf(-(xz + dz)));
            float n = tanhf(xnv + r * dn);
            float hv = (1.f - z) * n + z * hreg;
            hreg = hv;
            store_f32_sc(ys + (size_t)(t * NB + pb) * FEAT + pj, hv);
            if (t == NT - 1) hid[pb * FEAT + pj] = hv;
        }

        // -------- 2-hop barrier (round-10 verified) + piggybacked xp gate ------
        unsigned expected = (unsigned)(t + 1);
        __syncthreads();
        if (tid == 0) {
            bar_arrive(&flags[wg * FLAG_STRIDE], expected);
            if (xpcnt) {   // gate for NEXT step's xp rows; ordered by final sync
                int nx = (t + 1 < NT) ? (t + 1) : (NT - 1);
                bar_poll(&xpcnt[(nx >> 3) * FLAG_STRIDE], NXPT);
            }
        }
        if (wg < NGRP) {
            if (tid < GSZ) bar_poll(flags + (wg * GSZ + tid) * FLAG_STRIDE, expected);
            if (tid == 0) {
                asm volatile("global_store_dword %0, %1, off sc0 sc1"
                             :: "v"(&gflags[wg * FLAG_STRIDE]), "v"(expected) : "memory");
            }
        }
        if (tid < NGRP) bar_poll(gflags + tid * FLAG_STRIDE, expected);
        __builtin_amdgcn_sched_barrier(0);
        __syncthreads();
    }
}

// ---- phase 1: scan0 (gated on xp0 counters) || xp0 GEMM || gated xp1 GEMM ----
__global__ __launch_bounds__(256, 2) void phase1(
        float* __restrict__ xp, const float* __restrict__ Whh0,
        const float* __restrict__ bhh0, const float* __restrict__ h0,
        float* __restrict__ ys0, float* __restrict__ hid,
        unsigned* __restrict__ flags0, unsigned* __restrict__ gflags0,
        const float* __restrict__ xs,
        const float* __restrict__ Wih0, const float* __restrict__ bih0,
        unsigned* __restrict__ xpcnt,
        const float* __restrict__ Wih1, const float* __restrict__ bih1) {
    __shared__ __align__(16) char smem[SMEM_BYTES];
    int bid = blockIdx.x;
    if (bid < NWG) {
        scan_layer(smem, xp, Whh0, bhh0, h0, ys0, hid, flags0, gflags0, xpcnt);
    } else if (bid < NWG + (4096 / 128) * NXPT) {
        // xp0 producer tiles: coherent store + per-m counter
        int b2 = bid - NWG;
        int perGroup = 8 * NXPT;
        int g = b2 / perGroup, rix = b2 % perGroup;
        int n_t = rix / 8, m_t = g * 8 + (rix % 8);
        gemm_tile(smem, xs, Wih0, bih0, xp, G3, FEAT, m_t, n_t, 0,
                  1, &xpcnt[m_t * FLAG_STRIDE]);
    } else {
        // xp1 tiles: gated on scan0 progress; write xp IN PLACE (rows dead
        // for scan0 once gflags0 >= 8*(m_t+1)). Plain stores (next kernel
        // boundary flushes dirty L2 lines).
        int b2 = bid - NWG - (4096 / 128) * NXPT;
        int perGroup = 8 * NXPT;
        int g = b2 / perGroup, rix = b2 % perGroup;
        int n_t = rix / 8, m_t = g * 8 + (rix % 8);
        unsigned gate = (unsigned)((m_t + 1) * 8);
        if (threadIdx.x < NGRP) bar_poll(gflags0 + threadIdx.x * FLAG_STRIDE, gate);
        __builtin_amdgcn_sched_barrier(0);
        __syncthreads();
        gemm_tile(smem, ys0, Wih1, bih1, xp, G3, FEAT, m_t, n_t, 0, 0, nullptr);
    }
}

// ---------------- phase 2: scan1 || gated decoder GEMM -------------
__global__ __launch_bounds__(256, 2) void phase2(
        const float* __restrict__ xp, const float* __restrict__ Whh1,
        const float* __restrict__ bhh1, const float* __restrict__ h0b,
        float* __restrict__ ys1, float* __restrict__ hid1,
        unsigned* __restrict__ flags1, unsigned* __restrict__ gflags1,
        const float* __restrict__ emb, const float* __restrict__ dec_b,
        float* __restrict__ out) {
    __shared__ __align__(16) char smem[SMEM_BYTES];
    if (blockIdx.x < NWG) {
        scan_layer(smem, xp, Whh1, bhh1, h0b, ys1, hid1, flags1, gflags1, nullptr);
    } else {
        int bid = blockIdx.x - NWG;       // 4 groups x (250n x 8m)
        int perGroup = 8 * (VOCAB >> 7);
        int g = bid / perGroup, rix = bid % perGroup;
        int n_t = rix / 8, m_t = g * 8 + (rix % 8);
        unsigned gate = (unsigned)((m_t + 1) * 8);
        if (threadIdx.x < NGRP) bar_poll(gflags1 + threadIdx.x * FLAG_STRIDE, gate);
        __builtin_amdgcn_sched_barrier(0);
        __syncthreads();
        gemm_tile(smem, ys1, emb, dec_b, out, VOCAB, FEAT, m_t, n_t, 1, 0, nullptr);
    }
}

// ---------------- launcher ----------------
extern "C" void kernel_launch(void* const* d_in, const int* in_sizes, int n_in,
                              void* d_out, int out_size, void* d_ws, size_t ws_size,
                              hipStream_t stream) {
    const int*   x     = (const int*)d_in[0];
    const float* h0    = (const float*)d_in[1];
    const float* emb   = (const float*)d_in[2];
    const float* W_ih0 = (const float*)d_in[3];
    const float* W_hh0 = (const float*)d_in[4];
    const float* b_ih0 = (const float*)d_in[5];
    const float* b_hh0 = (const float*)d_in[6];
    const float* W_ih1 = (const float*)d_in[7];
    const float* W_hh1 = (const float*)d_in[8];
    const float* b_ih1 = (const float*)d_in[9];
    const float* b_hh1 = (const float*)d_in[10];
    const float* dec_b = (const float*)d_in[11];

    float* out = (float*)d_out;
    float* hid_out = out + (size_t)NB * NT * VOCAB;

    float* ws  = (float*)d_ws;
    float* xp  = ws;                                    // [4096][3072]
    float* xs  = xp + (size_t)4096 * 3072;              // gather out; then ys1 ring
    float* ys0 = xs + (size_t)4096 * 1024;              // [4096][1024] ring
    float* pad = ys0 + (size_t)4096 * 1024;
    unsigned* flags0  = (unsigned*)(pad + 2 * NB * FEAT);
    unsigned* gflags0 = flags0 + NWG * FLAG_STRIDE;
    unsigned* flags1  = gflags0 + NGRP * FLAG_STRIDE;
    unsigned* gflags1 = flags1 + NWG * FLAG_STRIDE;
    unsigned* xpcnt   = gflags1 + NGRP * FLAG_STRIDE;   // 32 counters, 128B apart
    float* ys1 = xs;                                    // ring (xs dead after xp0)

    // 0. zero all barrier state + xp counters
    hipMemsetAsync((void*)flags0, 0,
                   (2 * NWG + 2 * NGRP + 32) * FLAG_STRIDE * sizeof(unsigned),
                   stream);

    // 1. gather
    gather_kernel<<<dim3(NT * NB), dim3(256), 0, stream>>>(x, emb, xs);

    // 2. phase 1: scan0 (xp-gated) || xp0 GEMM (counter producer) || xp1 GEMM
    phase1<<<dim3(NWG + 2 * (4096 / 128) * NXPT), dim3(256), 0, stream>>>(
        xp, W_hh0, b_hh0, h0, ys0, hid_out, flags0, gflags0,
        xs, W_ih0, b_ih0, xpcnt, W_ih1, b_ih1);

    // 3. phase 2: scan1 || gated decoder GEMM
    phase2<<<dim3(NWG + (4096 / 128) * (VOCAB / 128)), dim3(256), 0, stream>>>(
        xp, W_hh1, b_hh1, h0 + NB * FEAT, ys1, hid_out + NB * FEAT,
        flags1, gflags1, emb, dec_b, out);
}